// Round 4
// baseline (852.029 us; speedup 1.0000x reference)
//
#include <hip/hip_runtime.h>
#include <hip/hip_bf16.h>
#include <math.h>

#define NROW 8
#define DT   2097152   // D = D1*D2
#define DD1  2048
#define DD2  1024
#define BATCH 512
#define GBLK 1024      // fused grid: 4 blocks/CU x 256 CU -> co-resident (lb(256,4) caps VGPR at 128)
#define NTHR (GBLK*256)

// ws layout:
//  [16777216)   vsumb : NROW*DT bf16   [n][k][l]
//  [50331648)   xb    : bf16 x
//  [69206016)   wt    : NROW*DT bf16   [n][l][k]
//  [102760448)  meta  : u32[1541]: hist2 @4, hist3 @132 (device-atomic RMW, LLC-coherent);
//                        m_pub @1412 (128 u32: level-2 m nibbles for cols 0..127, agent-scope)
//  [102801408)  bar   : u32[1] grid-barrier counter (memset 0 each launch)
//  [102801412)  fin   : u32[4]: 0=SMAX(max) 1=G2(max) 2=G3(max) (memset 0), 3=SMIN(min, memset 0xFF)

typedef __attribute__((ext_vector_type(8))) short short8;
typedef __attribute__((ext_vector_type(4))) float f32x4;

__device__ __forceinline__ unsigned fenc(float f){
  unsigned u = __float_as_uint(f);
  return (u & 0x80000000u) ? ~u : (u | 0x80000000u);
}
__device__ __forceinline__ float fdec(unsigned k){
  return (k & 0x80000000u) ? __uint_as_float(k ^ 0x80000000u) : __uint_as_float(~k);
}
__device__ __forceinline__ float sigmoid_ref(float z){
  #pragma clang fp contract(off)
  return 1.0f / (1.0f + expf(-z));
}
__device__ __forceinline__ unsigned short f2bf(float f){
  __hip_bfloat16 h = __float2bfloat16(f);
  return *reinterpret_cast<unsigned short*>(&h);
}
__device__ __forceinline__ float base1(float u, float s1, float inv_s1){
  #pragma clang fp contract(off)
  return s1 * floorf(u * inv_s1);
}
__device__ __forceinline__ void async16(const unsigned short* g, unsigned short* l){
  __builtin_amdgcn_global_load_lds((const __attribute__((address_space(1))) unsigned int*)g,
                                   (__attribute__((address_space(3))) unsigned int*)l, 16, 0, 0);
}

// ---- LLC-coherent scalar access (agent scope, relaxed) ----
__device__ __forceinline__ void ast(unsigned* p, unsigned v){
  __hip_atomic_store(p, v, __ATOMIC_RELAXED, __HIP_MEMORY_SCOPE_AGENT);
}
__device__ __forceinline__ unsigned ald(const unsigned* p){
  return __hip_atomic_load(p, __ATOMIC_RELAXED, __HIP_MEMORY_SCOPE_AGENT);
}

// fence-free grid barrier (all cross-block data moves through LLC-coherent atomics).
__device__ __forceinline__ void gbar(unsigned* cnt, int t, unsigned target){
  __syncthreads();
  if (t == 0){
    __hip_atomic_fetch_add(cnt, 1u, __ATOMIC_RELAXED, __HIP_MEMORY_SCOPE_AGENT);
    while (__hip_atomic_load(cnt, __ATOMIC_RELAXED, __HIP_MEMORY_SCOPE_AGENT) < target)
      __builtin_amdgcn_s_sleep(8);
  }
  __syncthreads();
}

// ---- 8-element sorting networks (Batcher odd-even, 19 comparators) ----
#define CSWAPV(a,b) { float _lo=fminf(a,b), _hi=fmaxf(a,b); a=_lo; b=_hi; }
__device__ __forceinline__ void sort8v(float v[8]){
  CSWAPV(v[0],v[1]) CSWAPV(v[2],v[3]) CSWAPV(v[4],v[5]) CSWAPV(v[6],v[7])
  CSWAPV(v[0],v[2]) CSWAPV(v[1],v[3]) CSWAPV(v[4],v[6]) CSWAPV(v[5],v[7])
  CSWAPV(v[1],v[2]) CSWAPV(v[5],v[6])
  CSWAPV(v[0],v[4]) CSWAPV(v[1],v[5]) CSWAPV(v[2],v[6]) CSWAPV(v[3],v[7])
  CSWAPV(v[2],v[4]) CSWAPV(v[3],v[5])
  CSWAPV(v[1],v[2]) CSWAPV(v[3],v[4]) CSWAPV(v[5],v[6])
}
__device__ __forceinline__ void cswapkv(float&av,int&ai,float&bv,int&bi){
  bool sw = (av > bv) || ((av == bv) && (ai > bi));   // lexicographic -> stable
  float nav = sw ? bv : av; float nbv = sw ? av : bv;
  int   nai = sw ? bi : ai; int   nbi = sw ? ai : bi;
  av = nav; bv = nbv; ai = nai; bi = nbi;
}
#define CSWAPK(i,j) cswapkv(v[i],ix[i],v[j],ix[j]);
__device__ __forceinline__ void sort8kv(float v[8], int ix[8]){
  CSWAPK(0,1) CSWAPK(2,3) CSWAPK(4,5) CSWAPK(6,7)
  CSWAPK(0,2) CSWAPK(1,3) CSWAPK(4,6) CSWAPK(5,7)
  CSWAPK(1,2) CSWAPK(5,6)
  CSWAPK(0,4) CSWAPK(1,5) CSWAPK(2,6) CSWAPK(3,7)
  CSWAPK(2,4) CSWAPK(3,5)
  CSWAPK(1,2) CSWAPK(3,4) CSWAPK(5,6)
}

// block-wide u32 max; result valid in ALL threads.
__device__ __forceinline__ unsigned blk_umax(unsigned v, unsigned* red, int t){
  __syncthreads();
  red[t] = v;
  __syncthreads();
  for (int o = 128; o > 0; o >>= 1){
    if (t < o) red[t] = max(red[t], red[t+o]);
    __syncthreads();
  }
  return red[0];
}

// ---- rank/top-5/msp tables, REPLICATED per block (deterministic: identical inputs
// -> identical FP sequence -> identical tables everywhere). Reads: 128 hist words
// (LLC atomics), U cols 0..127 (read-only, cached), m_pub for LEVEL 3. Writes: LDS only.
template<int LEVEL>
__device__ void small_phase(int t, float gmax, int hoff,
                            float s1, float inv_s1, float s2,
                            const float* __restrict__ U, const float* __restrict__ tm,
                            unsigned* __restrict__ meta,
                            int* cs, int* rk, int* redk,
                            int* top_code, int* top_rank, int* w0cnt,
                            int* fr_s, unsigned* bits_s, float* msp_s){
  #pragma clang fp contract(off)
  int c = t;
  int lane = t & 63;
  if (c < 128){
    cs[c] = (int)ald(&meta[hoff + c]);
    bool present = cs[c] > 0;
    unsigned long long bm = __ballot(present);
    int r = (int)__popcll(bm & ((1ull << lane) - 1ull));
    if (c == 63) *w0cnt = (int)__popcll(bm);
    rk[c] = r;
  }
  __syncthreads();
  if (c >= 64 && c < 128) rk[c] += *w0cnt;
  __syncthreads();
  for (int k = 0; k < 5; ++k){            // top-5 argsort(-counts), ties -> lowest index
    if (c < 128) redk[c] = (cs[c] << 7) | (127 - c);
    __syncthreads();
    for (int o = 64; o > 0; o >>= 1){
      if (c < o) redk[c] = max(redk[c], redk[c+o]);
      __syncthreads();
    }
    if (c == 0){
      int best = 127 - (redk[0] & 127);
      top_code[k] = best; top_rank[k] = rk[best];
      cs[best] = -1;
    }
    __syncthreads();
  }
  if (c < 128){
    int besti = -1, sel = 0;
    #pragma unroll
    for (int j = 0; j < 5; ++j){          // argmax first-wins over shared-bit counts
      int inter = __popc(c & top_code[j]);
      if (inter > besti){ besti = inter; sel = j; }
    }
    bool is_top = false;
    #pragma unroll
    for (int j = 0; j < 5; ++j) is_top = is_top || (rk[c] == top_rank[j]);
    fr_s[c] = is_top ? rk[c] : top_rank[sel];
    // full-fidelity msp/scheme for col c: recompute sorted residuals (bit-exact main path)
    unsigned mp = 0u;
    if (LEVEL == 3) mp = ald(&meta[1412 + c]);
    float res[8];
    #pragma unroll
    for (int i = 0; i < 8; ++i){
      float uv = U[(size_t)i*DT + c];
      float bval = base1(uv, s1, inv_s1);
      if (LEVEL == 3){
        int mi = (int)((mp >> (4*i)) & 15u) - 8;
        bval = bval + s2 * (float)mi;
      }
      res[i] = uv - bval;
    }
    sort8v(res);
    float thr = sigmoid_ref(tm[c >> 11]);
    unsigned bits = 0;
    #pragma unroll
    for (int i = 0; i < 7; ++i){
      float dn  = (res[i+1] - res[i]) / gmax;
      float z   = (dn - thr) / 0.01f;
      float msp = sigmoid_ref(z);
      msp_s[c*7 + i] = msp;
      bits |= ((unsigned)(int)rintf(msp)) << i;
    }
    bits_s[c] = bits;
  }
  __syncthreads();   // tables ready for whole block
}

// ---- fused quant pipeline ----
__global__ __launch_bounds__(256, 4) void k_fused(const float* __restrict__ U,
                                                  const float* __restrict__ x,
                                                  unsigned short* __restrict__ xb,
                                                  unsigned short* __restrict__ vsumb,
                                                  const float* __restrict__ tm,
                                                  unsigned* __restrict__ meta,
                                                  unsigned* __restrict__ bar,
                                                  unsigned* __restrict__ fin){
  #pragma clang fp contract(off)
  __shared__ unsigned redA[256], redB[256];
  __shared__ int hist[128];
  __shared__ float qcol[8*256];            // [row][t] own-lane scatter, bank = t%32 (conflict-free)
  __shared__ int cs[128], rk[128], redk[128];
  __shared__ int top_code[5], top_rank[5];
  __shared__ int w0cnt;
  __shared__ int fr_s[128];
  __shared__ unsigned bits_s[128];
  __shared__ float msp_s[896];
  __shared__ unsigned bcA, bcB;

  const int t = threadIdx.x, b = blockIdx.x;
  const int g = b*256 + t;
  const int lane = t & 63;
  const int d[2] = { 4*g, 4*g + 4*NTHR };  // column base per quad (both fully coalesced)

  // ---- P0: zero hists, x->bf16, global min/max of U ----
  if (b == 0 && t < 128){ ast(&meta[4+t], 0u); ast(&meta[132+t], 0u); }
  {
    const float4* x4 = (const float4*)x;   // 2,097,152 float4 over 262,144 threads = 8 each
    #pragma unroll
    for (int i = 0; i < 8; ++i){
      int idx = g + i*NTHR;
      float4 v = x4[idx];
      ushort4 o;
      o.x = f2bf(v.x); o.y = f2bf(v.y); o.z = f2bf(v.z); o.w = f2bf(v.w);
      *(ushort4*)(xb + (size_t)idx*4) = o;
    }
  }
  {
    float mx = -INFINITY, mn = INFINITY;
    #pragma unroll
    for (int q = 0; q < 2; ++q){
      #pragma unroll
      for (int i = 0; i < 8; ++i){
        float4 v = *(const float4*)(U + (size_t)i*DT + d[q]);
        mx = fmaxf(mx, fmaxf(fmaxf(v.x,v.y), fmaxf(v.z,v.w)));
        mn = fminf(mn, fminf(fminf(v.x,v.y), fminf(v.z,v.w)));
      }
    }
    redA[t] = fenc(mx); redB[t] = fenc(mn);
    __syncthreads();
    for (int o = 128; o > 0; o >>= 1){
      if (t < o){ redA[t] = max(redA[t], redA[t+o]); redB[t] = min(redB[t], redB[t+o]); }
      __syncthreads();
    }
    if (t == 0){ atomicMax(&fin[0], redA[0]); atomicMin(&fin[3], redB[0]); }
  }
  gbar(bar, t, 1*GBLK);

  // ---- s1 (single-word broadcast; max/min order-independent -> bit-identical) ----
  if (t == 0){ bcA = ald(&fin[0]); bcB = ald(&fin[3]); }
  __syncthreads();
  float s1 = (fdec(bcA) - fdec(bcB)) / 3.0f;
  float inv_s1 = 1.0f / s1;
  float s2 = s1 / 5.0f;

  // ---- P1: level-2 delta gmax ----
  {
    unsigned dmax = 0u;
    #pragma unroll
    for (int q = 0; q < 2; ++q){
      float4 u4[8];
      #pragma unroll
      for (int i = 0; i < 8; ++i) u4[i] = *(const float4*)(U + (size_t)i*DT + d[q]);
      #pragma unroll
      for (int c = 0; c < 4; ++c){
        float res[8];
        #pragma unroll
        for (int i = 0; i < 8; ++i){
          float uv = ((const float*)&u4[i])[c];
          res[i] = uv - base1(uv, s1, inv_s1);
        }
        sort8v(res);
        float m = 0.0f;
        #pragma unroll
        for (int i = 0; i < 7; ++i) m = fmaxf(m, res[i+1] - res[i]);
        dmax = max(dmax, __float_as_uint(m));   // deltas >= 0: bits order-preserving
      }
    }
    unsigned r = blk_umax(dmax, redA, t);
    if (t == 0) atomicMax(&fin[1], r);
  }
  gbar(bar, t, 2*GBLK);
  if (t == 0) bcA = ald(&fin[1]);
  __syncthreads();
  float gmax2 = __uint_as_float(bcA);

  // ---- P2: level-2 codes + histogram (7-ballot match-any) ----
  unsigned cdq[2];
  {
    if (t < 128) hist[t] = 0;
    __syncthreads();
    float inv_g = 1.0f / gmax2;
    #pragma unroll
    for (int q = 0; q < 2; ++q){
      float4 u4[8];
      #pragma unroll
      for (int i = 0; i < 8; ++i) u4[i] = *(const float4*)(U + (size_t)i*DT + d[q]);
      float thr = sigmoid_ref(tm[d[q] >> 11]);
      unsigned cpack = 0u;
      #pragma unroll
      for (int c = 0; c < 4; ++c){
        float res[8];
        #pragma unroll
        for (int i = 0; i < 8; ++i){
          float uv = ((const float*)&u4[i])[c];
          res[i] = uv - base1(uv, s1, inv_s1);
        }
        sort8v(res);
        int cd = 0;
        #pragma unroll
        for (int i = 0; i < 7; ++i){
          float dn = (res[i+1] - res[i]) * inv_g;
          cd = (cd << 1) | ((dn > thr) ? 1 : 0);
        }
        cpack |= (unsigned)cd << (8*c);
        // match-any: fixed-cost 7 ballots, one LDS atomic per distinct code per wave
        unsigned long long mset = ~0ull;
        #pragma unroll
        for (int bi = 0; bi < 7; ++bi){
          bool bit = ((cd >> bi) & 1) != 0;
          unsigned long long bb = __ballot(bit);
          mset &= bit ? bb : ~bb;
        }
        int leader = (int)__ffsll(mset) - 1;
        if (lane == leader) atomicAdd(&hist[cd], (int)__popcll(mset));
      }
      cdq[q] = cpack;
    }
    __syncthreads();
    if (t < 128){ int h = hist[t]; if (h) atomicAdd((int*)&meta[4 + t], h); }
  }
  gbar(bar, t, 3*GBLK);

  // ---- small2: replicated per block -> fr_s/bits_s/msp_s in LDS ----
  small_phase<2>(t, gmax2, 4, s1, inv_s1, s2, U, tm, meta,
                 cs, rk, redk, top_code, top_rank, &w0cnt, fr_s, bits_s, msp_s);

  // ---- P4: level-2 apply -> m nibbles in regs + fused level-3 gmax ----
  unsigned mpk[2][4];
  {
    float s = s2, inv_s = 1.0f / s;
    unsigned dmax = 0u;
    #pragma unroll
    for (int q = 0; q < 2; ++q){
      float4 u4[8];
      #pragma unroll
      for (int i = 0; i < 8; ++i) u4[i] = *(const float4*)(U + (size_t)i*DT + d[q]);
      #pragma unroll
      for (int c = 0; c < 4; ++c){
        float v[8]; int ix[8];
        #pragma unroll
        for (int i = 0; i < 8; ++i){
          float uv = ((const float*)&u4[i])[c];
          v[i] = uv - base1(uv, s1, inv_s1);
          ix[i] = i;
        }
        sort8kv(v, ix);                    // stable: reproduces jnp.argsort
        int cr = fr_s[(cdq[q] >> (8*c)) & 0x7f];
        unsigned sb = bits_s[cr];
        float vv[8]; bool bl[8];
        float buf = 0.0f, cnt = 0.0f, gq = 1.0f; bool reset = false;
        #pragma unroll
        for (int i = 0; i < 8; ++i){       // reference scan; mean via rcp (<=1.5ulp)
          buf = reset ? v[i] : (buf + v[i]);
          cnt = reset ? 1.0f : (cnt + 1.0f);
          gq  = reset ? 1.0f : gq;
          float m = buf * __builtin_amdgcn_rcpf(cnt);
          if (i == 7){ vv[7] = gq * m; bl[7] = true; }
          else {
            float msp = msp_s[cr*7 + i];
            bool bv = ((sb >> i) & 1u) != 0u;
            vv[i] = bv ? ((gq * msp) * m) : 0.0f;
            bl[i] = bv;
            gq = bv ? gq : (gq * (1.0f - msp));
            reset = bv;
          }
        }
        float out = vv[7];
        float inner[8];
        inner[7] = out;
        for (int i = 6; i >= 0; --i){ if (bl[i]) out = vv[i]; inner[i] = out; }
        unsigned mp = 0u;
        #pragma unroll
        for (int i = 0; i < 8; ++i){       // nibble-scatter to original row (no LDS needed)
          float mf = floorf(inner[i] * inv_s);
          int mi = (int)mf;
          mi = max(-8, min(7, mi));
          mp |= (unsigned)(mi + 8) << (4*ix[i]);
        }
        mpk[q][c] = mp;
        float r3[8];
        #pragma unroll
        for (int r = 0; r < 8; ++r){       // bit-exact next-level residual: u - (b + s*mi)
          int mi = (int)((mp >> (4*r)) & 15u) - 8;
          float uv = ((const float*)&u4[r])[c];
          float qv = s * (float)mi;
          float vn = base1(uv, s1, inv_s1) + qv;
          r3[r] = uv - vn;
        }
        sort8v(r3);
        float m = 0.0f;
        #pragma unroll
        for (int i = 0; i < 7; ++i) m = fmaxf(m, r3[i+1] - r3[i]);
        dmax = max(dmax, __float_as_uint(m));
      }
    }
    // publish level-2 m for cols 0..127 (block 0, threads 0..31 own them at q=0)
    if (b == 0 && t < 32){
      #pragma unroll
      for (int c = 0; c < 4; ++c) ast(&meta[1412 + 4*t + c], mpk[0][c]);
    }
    unsigned r = blk_umax(dmax, redA, t);
    if (t == 0) atomicMax(&fin[2], r);
  }
  gbar(bar, t, 4*GBLK);
  if (t == 0) bcA = ald(&fin[2]);
  __syncthreads();
  float gmax3 = __uint_as_float(bcA);

  // ---- P5: level-3 codes + histogram ----
  {
    __syncthreads();
    if (t < 128) hist[t] = 0;
    __syncthreads();
    float inv_g = 1.0f / gmax3;
    #pragma unroll
    for (int q = 0; q < 2; ++q){
      float4 u4[8];
      #pragma unroll
      for (int i = 0; i < 8; ++i) u4[i] = *(const float4*)(U + (size_t)i*DT + d[q]);
      float thr = sigmoid_ref(tm[d[q] >> 11]);
      unsigned cpack = 0u;
      #pragma unroll
      for (int c = 0; c < 4; ++c){
        float res[8];
        #pragma unroll
        for (int i = 0; i < 8; ++i){
          int mi = (int)((mpk[q][c] >> (4*i)) & 15u) - 8;
          float uv = ((const float*)&u4[i])[c];
          res[i] = uv - (base1(uv, s1, inv_s1) + s2 * (float)mi);   // == vn2_of path
        }
        sort8v(res);
        int cd = 0;
        #pragma unroll
        for (int i = 0; i < 7; ++i){
          float dn = (res[i+1] - res[i]) * inv_g;
          cd = (cd << 1) | ((dn > thr) ? 1 : 0);
        }
        cpack |= (unsigned)cd << (8*c);
        unsigned long long mset = ~0ull;
        #pragma unroll
        for (int bi = 0; bi < 7; ++bi){
          bool bit = ((cd >> bi) & 1) != 0;
          unsigned long long bb = __ballot(bit);
          mset &= bit ? bb : ~bb;
        }
        int leader = (int)__ffsll(mset) - 1;
        if (lane == leader) atomicAdd(&hist[cd], (int)__popcll(mset));
      }
      cdq[q] = cpack;
    }
    __syncthreads();
    if (t < 128){ int h = hist[t]; if (h) atomicAdd((int*)&meta[132 + t], h); }
  }
  gbar(bar, t, 5*GBLK);

  // ---- small3: replicated per block ----
  small_phase<3>(t, gmax3, 132, s1, inv_s1, s2, U, tm, meta,
                 cs, rk, redk, top_code, top_rank, &w0cnt, fr_s, bits_s, msp_s);

  // ---- P7: level-3 apply -> final vsum bf16 [n][k][l] ----
  {
    float s = s2 / 17.0f, inv_s = 1.0f / s;
    #pragma unroll
    for (int q = 0; q < 2; ++q){
      float4 u4[8];
      #pragma unroll
      for (int i = 0; i < 8; ++i) u4[i] = *(const float4*)(U + (size_t)i*DT + d[q]);
      ushort4 ov[8];
      #pragma unroll
      for (int c = 0; c < 4; ++c){
        float v[8]; int ix[8];
        #pragma unroll
        for (int i = 0; i < 8; ++i){
          int mi = (int)((mpk[q][c] >> (4*i)) & 15u) - 8;
          float uv = ((const float*)&u4[i])[c];
          v[i] = uv - (base1(uv, s1, inv_s1) + s2 * (float)mi);
          ix[i] = i;
        }
        sort8kv(v, ix);
        int cr = fr_s[(cdq[q] >> (8*c)) & 0x7f];
        unsigned sb = bits_s[cr];
        float vv[8]; bool bl[8];
        float buf = 0.0f, cnt = 0.0f, gq = 1.0f; bool reset = false;
        #pragma unroll
        for (int i = 0; i < 8; ++i){
          buf = reset ? v[i] : (buf + v[i]);
          cnt = reset ? 1.0f : (cnt + 1.0f);
          gq  = reset ? 1.0f : gq;
          float m = buf * __builtin_amdgcn_rcpf(cnt);
          if (i == 7){ vv[7] = gq * m; bl[7] = true; }
          else {
            float msp = msp_s[cr*7 + i];
            bool bv = ((sb >> i) & 1u) != 0u;
            vv[i] = bv ? ((gq * msp) * m) : 0.0f;
            bl[i] = bv;
            gq = bv ? gq : (gq * (1.0f - msp));
            reset = bv;
          }
        }
        float out = vv[7];
        float inner[8];
        inner[7] = out;
        for (int i = 6; i >= 0; --i){ if (bl[i]) out = vv[i]; inner[i] = out; }
        // own-lane LDS scatter (float floor-count, unclamped — matches verified level-3 path)
        #pragma unroll
        for (int i = 0; i < 8; ++i) qcol[ix[i]*256 + t] = floorf(inner[i] * inv_s);
        #pragma unroll
        for (int r = 0; r < 8; ++r){
          int mi = (int)((mpk[q][c] >> (4*r)) & 15u) - 8;
          float uv = ((const float*)&u4[r])[c];
          float bv = base1(uv, s1, inv_s1) + s2 * (float)mi;
          float qv = s * qcol[r*256 + t];
          ((unsigned short*)&ov[r])[c] = f2bf(bv + qv);
        }
      }
      #pragma unroll
      for (int r = 0; r < 8; ++r)
        *(ushort4*)(vsumb + (size_t)r*DT + d[q]) = ov[r];
    }
  }
}

// transpose: wt[n][l][k] = vsumb[n][k][l] (both bf16); 64(k) x 64(l) tiles
__global__ __launch_bounds__(256) void k_wt(const unsigned short* __restrict__ vsumb,
                                            unsigned short* __restrict__ wt){
  __shared__ unsigned short tile[64][68];
  int t = threadIdx.x;
  int c4 = t & 15, r0 = t >> 4;
  int n = blockIdx.z, k0 = blockIdx.y*64, l0 = blockIdx.x*64;
  const unsigned short* src = vsumb + (size_t)n*DT;
  #pragma unroll
  for (int i = 0; i < 4; ++i){
    int r = r0 + i*16;                     // k index in tile
    ushort4 v = *(const ushort4*)(src + (size_t)(k0+r)*DD2 + l0 + c4*4);
    *(ushort4*)&tile[r][c4*4] = v;
  }
  __syncthreads();
  unsigned short* dst = wt + (size_t)n*DT;
  #pragma unroll
  for (int i = 0; i < 4; ++i){
    int rl = r0 + i*16;                    // l index in tile
    ushort4 o;
    o.x = tile[c4*4+0][rl]; o.y = tile[c4*4+1][rl];
    o.z = tile[c4*4+2][rl]; o.w = tile[c4*4+3][rl];
    *(ushort4*)(dst + (size_t)(l0+rl)*DD1 + k0 + c4*4) = o;
  }
}

// MFMA GEMM: out[b,n,l] = sum_k xb[b,n,k] * wt[n,l,k]; 64(M)x128(N) tile, BK=64, 4 waves
__global__ __launch_bounds__(256) void k_gemm(const unsigned short* __restrict__ xb,
                                              const unsigned short* __restrict__ wt,
                                              float* __restrict__ out){
  __shared__ __align__(16) unsigned short As[64*64];
  __shared__ __align__(16) unsigned short Bs[128*64];
  int t = threadIdx.x;
  int lane = t & 63, wv = t >> 6;
  int n  = blockIdx.z;
  int b0 = blockIdx.y * 64;
  int l0 = blockIdx.x * 128;
  int wm = (wv >> 1) * 32, wn = (wv & 1) * 64;
  int col = lane & 15, quad = lane >> 4;
  int arow = lane >> 3, aseg = lane & 7;
  const unsigned short* wtn = wt + (size_t)n*DT;
  f32x4 acc[2][4] = {};
  for (int k0 = 0; k0 < DD1; k0 += 64){
    #pragma unroll
    for (int i = 0; i < 2; ++i){
      int row = wv*16 + i*8 + arow;
      const unsigned short* g = xb + (((size_t)(b0+row)*NROW + n)*DD1 + k0 + aseg*8);
      async16(g, &As[(wv*16 + i*8)*64]);
    }
    #pragma unroll
    for (int i = 0; i < 4; ++i){
      int row = wv*32 + i*8 + arow;
      const unsigned short* g = wtn + ((size_t)(l0+row)*DD1 + k0 + aseg*8);
      async16(g, &Bs[(wv*32 + i*8)*64]);
    }
    __syncthreads();
    #pragma unroll
    for (int ks = 0; ks < 2; ++ks){
      int kq = ks*32 + quad*8;
      short8 af[2], bfr[4];
      #pragma unroll
      for (int mi = 0; mi < 2; ++mi) af[mi]  = *(const short8*)&As[(wm + mi*16 + col)*64 + kq];
      #pragma unroll
      for (int ni = 0; ni < 4; ++ni) bfr[ni] = *(const short8*)&Bs[(wn + ni*16 + col)*64 + kq];
      #pragma unroll
      for (int mi = 0; mi < 2; ++mi)
        #pragma unroll
        for (int ni = 0; ni < 4; ++ni)
          acc[mi][ni] = __builtin_amdgcn_mfma_f32_16x16x32_bf16(af[mi], bfr[ni], acc[mi][ni], 0, 0, 0);
    }
    __syncthreads();
  }
  #pragma unroll
  for (int mi = 0; mi < 2; ++mi)
    #pragma unroll
    for (int ni = 0; ni < 4; ++ni)
      #pragma unroll
      for (int r = 0; r < 4; ++r){
        int bb = b0 + wm + mi*16 + quad*4 + r;
        int l = l0 + wn + ni*16 + col;
        out[((size_t)bb*NROW + n)*DD2 + l] = acc[mi][ni][r];
      }
}

extern "C" void kernel_launch(void* const* d_in, const int* in_sizes, int n_in,
                              void* d_out, int out_size, void* d_ws, size_t ws_size,
                              hipStream_t stream){
  const float* x  = (const float*)d_in[0];
  const float* U  = (const float*)d_in[1];
  const float* tm = (const float*)d_in[2];
  float* out = (float*)d_out;
  unsigned short* vsumb = (unsigned short*)((unsigned char*)d_ws + 16777216);
  unsigned short* xb    = (unsigned short*)((unsigned char*)d_ws + 50331648);
  unsigned short* wt    = (unsigned short*)((unsigned char*)d_ws + 69206016);
  unsigned* meta  = (unsigned*)((unsigned char*)d_ws + 102760448);
  unsigned* bar   = (unsigned*)((unsigned char*)d_ws + 102801408);
  unsigned* fin   = (unsigned*)((unsigned char*)d_ws + 102801412);
  (void)in_sizes; (void)n_in; (void)out_size; (void)ws_size;

  hipMemsetAsync(bar, 0, 16, stream);        // bar=0, fin[0..2]=0 (max-init)
  hipMemsetAsync(fin + 3, 0xFF, 4, stream);  // fin[3]=0xFFFFFFFF (min-init)
  k_fused<<<GBLK, 256, 0, stream>>>(U, x, xb, vsumb, tm, meta, bar, fin);
  k_wt  <<<dim3(DD2/64, DD1/64, NROW), 256, 0, stream>>>(vsumb, wt);
  k_gemm<<<dim3(DD2/128, BATCH/64, NROW), 256, 0, stream>>>(xb, wt, out);
}

// Round 5
// 643.550 us; speedup vs baseline: 1.3240x; 1.3240x over previous
//
#include <hip/hip_runtime.h>
#include <hip/hip_bf16.h>
#include <math.h>

#define NROW 8
#define DT   2097152   // D = D1*D2
#define DD1  2048
#define DD2  1024
#define BATCH 512
#define GBLK 512       // fused grid: >=2 blocks/CU at worst-case VGPR=256 -> co-resident
#define NTHR (GBLK*256)
#define NQ   4         // column quads per thread (16 cols)

// ws layout:
//  [16777216)   vsumb : NROW*DT bf16   [n][k][l]
//  [50331648)   xb    : bf16 x
//  [69206016)   wt    : NROW*DT bf16   [n][l][k]
//  [102760448)  meta  : u32[1541]: hist2 @4, hist3 @132 (device-atomic RMW, LLC-coherent);
//                        m_pub @1412 (128 u32: level-2 m nibbles for cols 0..127)
//  [102801408)  bar   : u32[1] grid-barrier counter (memset 0 each launch)
//  [102801412)  fin   : u32[4]: 0=SMAX(max) 1=G2(max) 2=G3(max) (memset 0), 3=SMIN(min, memset 0xFF)

typedef __attribute__((ext_vector_type(8))) short short8;
typedef __attribute__((ext_vector_type(4))) float f32x4;

__device__ __forceinline__ unsigned fenc(float f){
  unsigned u = __float_as_uint(f);
  return (u & 0x80000000u) ? ~u : (u | 0x80000000u);
}
__device__ __forceinline__ float fdec(unsigned k){
  return (k & 0x80000000u) ? __uint_as_float(k ^ 0x80000000u) : __uint_as_float(~k);
}
__device__ __forceinline__ float sigmoid_ref(float z){
  #pragma clang fp contract(off)
  return 1.0f / (1.0f + expf(-z));
}
__device__ __forceinline__ unsigned short f2bf(float f){
  __hip_bfloat16 h = __float2bfloat16(f);
  return *reinterpret_cast<unsigned short*>(&h);
}
__device__ __forceinline__ float base1(float u, float s1, float inv_s1){
  #pragma clang fp contract(off)
  return s1 * floorf(u * inv_s1);
}
__device__ __forceinline__ void async16(const unsigned short* g, unsigned short* l){
  __builtin_amdgcn_global_load_lds((const __attribute__((address_space(1))) unsigned int*)g,
                                   (__attribute__((address_space(3))) unsigned int*)l, 16, 0, 0);
}

// ---- LLC-coherent scalar access (agent scope, relaxed) ----
__device__ __forceinline__ void ast(unsigned* p, unsigned v){
  __hip_atomic_store(p, v, __ATOMIC_RELAXED, __HIP_MEMORY_SCOPE_AGENT);
}
__device__ __forceinline__ unsigned ald(const unsigned* p){
  return __hip_atomic_load(p, __ATOMIC_RELAXED, __HIP_MEMORY_SCOPE_AGENT);
}

// fence-free grid barrier (all cross-block data moves through LLC-coherent atomics).
__device__ __forceinline__ void gbar(unsigned* cnt, int t, unsigned target){
  __syncthreads();
  if (t == 0){
    __hip_atomic_fetch_add(cnt, 1u, __ATOMIC_RELAXED, __HIP_MEMORY_SCOPE_AGENT);
    while (__hip_atomic_load(cnt, __ATOMIC_RELAXED, __HIP_MEMORY_SCOPE_AGENT) < target)
      __builtin_amdgcn_s_sleep(8);
  }
  __syncthreads();
}

// ---- 8-element sorting networks (Batcher odd-even, 19 comparators) ----
#define CSWAPV(a,b) { float _lo=fminf(a,b), _hi=fmaxf(a,b); a=_lo; b=_hi; }
__device__ __forceinline__ void sort8v(float v[8]){
  CSWAPV(v[0],v[1]) CSWAPV(v[2],v[3]) CSWAPV(v[4],v[5]) CSWAPV(v[6],v[7])
  CSWAPV(v[0],v[2]) CSWAPV(v[1],v[3]) CSWAPV(v[4],v[6]) CSWAPV(v[5],v[7])
  CSWAPV(v[1],v[2]) CSWAPV(v[5],v[6])
  CSWAPV(v[0],v[4]) CSWAPV(v[1],v[5]) CSWAPV(v[2],v[6]) CSWAPV(v[3],v[7])
  CSWAPV(v[2],v[4]) CSWAPV(v[3],v[5])
  CSWAPV(v[1],v[2]) CSWAPV(v[3],v[4]) CSWAPV(v[5],v[6])
}
__device__ __forceinline__ void cswapkv(float&av,int&ai,float&bv,int&bi){
  bool sw = (av > bv) || ((av == bv) && (ai > bi));   // lexicographic -> stable
  float nav = sw ? bv : av; float nbv = sw ? av : bv;
  int   nai = sw ? bi : ai; int   nbi = sw ? ai : bi;
  av = nav; bv = nbv; ai = nai; bi = nbi;
}
#define CSWAPK(i,j) cswapkv(v[i],ix[i],v[j],ix[j]);
__device__ __forceinline__ void sort8kv(float v[8], int ix[8]){
  CSWAPK(0,1) CSWAPK(2,3) CSWAPK(4,5) CSWAPK(6,7)
  CSWAPK(0,2) CSWAPK(1,3) CSWAPK(4,6) CSWAPK(5,7)
  CSWAPK(1,2) CSWAPK(5,6)
  CSWAPK(0,4) CSWAPK(1,5) CSWAPK(2,6) CSWAPK(3,7)
  CSWAPK(2,4) CSWAPK(3,5)
  CSWAPK(1,2) CSWAPK(3,4) CSWAPK(5,6)
}

// block-wide u32 max; result valid in ALL threads.
__device__ __forceinline__ unsigned blk_umax(unsigned v, unsigned* red, int t){
  __syncthreads();
  red[t] = v;
  __syncthreads();
  for (int o = 128; o > 0; o >>= 1){
    if (t < o) red[t] = max(red[t], red[t+o]);
    __syncthreads();
  }
  return red[0];
}

// ---- rank/top-5/msp tables, REPLICATED per block (deterministic: identical inputs
// -> identical FP sequence -> identical tables everywhere). Reads: 128 hist words
// (LLC atomics), U cols 0..127 (read-only, cached), m_pub for LEVEL 3. Writes: LDS only.
template<int LEVEL>
__device__ void small_phase(int t, float gmax, int hoff,
                            float s1, float inv_s1, float s2,
                            const float* __restrict__ U, const float* __restrict__ tm,
                            unsigned* __restrict__ meta,
                            int* cs, int* rk, int* redk,
                            int* top_code, int* top_rank, int* w0cnt,
                            int* fr_s, unsigned* bits_s, float* msp_s){
  #pragma clang fp contract(off)
  int c = t;
  int lane = t & 63;
  if (c < 128){
    cs[c] = (int)ald(&meta[hoff + c]);
    bool present = cs[c] > 0;
    unsigned long long bm = __ballot(present);
    int r = (int)__popcll(bm & ((1ull << lane) - 1ull));
    if (c == 63) *w0cnt = (int)__popcll(bm);
    rk[c] = r;
  }
  __syncthreads();
  if (c >= 64 && c < 128) rk[c] += *w0cnt;
  __syncthreads();
  for (int k = 0; k < 5; ++k){            // top-5 argsort(-counts), ties -> lowest index
    if (c < 128) redk[c] = (cs[c] << 7) | (127 - c);
    __syncthreads();
    for (int o = 64; o > 0; o >>= 1){
      if (c < o) redk[c] = max(redk[c], redk[c+o]);
      __syncthreads();
    }
    if (c == 0){
      int best = 127 - (redk[0] & 127);
      top_code[k] = best; top_rank[k] = rk[best];
      cs[best] = -1;
    }
    __syncthreads();
  }
  if (c < 128){
    int besti = -1, sel = 0;
    #pragma unroll
    for (int j = 0; j < 5; ++j){          // argmax first-wins over shared-bit counts
      int inter = __popc(c & top_code[j]);
      if (inter > besti){ besti = inter; sel = j; }
    }
    bool is_top = false;
    #pragma unroll
    for (int j = 0; j < 5; ++j) is_top = is_top || (rk[c] == top_rank[j]);
    fr_s[c] = is_top ? rk[c] : top_rank[sel];
    // full-fidelity msp/scheme for col c: recompute sorted residuals (bit-exact main path)
    unsigned mp = 0u;
    if (LEVEL == 3) mp = ald(&meta[1412 + c]);
    float res[8];
    #pragma unroll
    for (int i = 0; i < 8; ++i){
      float uv = U[(size_t)i*DT + c];
      float bval = base1(uv, s1, inv_s1);
      if (LEVEL == 3){
        int mi = (int)((mp >> (4*i)) & 15u) - 8;
        bval = bval + s2 * (float)mi;
      }
      res[i] = uv - bval;
    }
    sort8v(res);
    float thr = sigmoid_ref(tm[c >> 11]);
    unsigned bits = 0;
    #pragma unroll
    for (int i = 0; i < 7; ++i){
      float dn  = (res[i+1] - res[i]) / gmax;
      float z   = (dn - thr) / 0.01f;
      float msp = sigmoid_ref(z);
      msp_s[c*7 + i] = msp;
      bits |= ((unsigned)(int)rintf(msp)) << i;
    }
    bits_s[c] = bits;
  }
  __syncthreads();   // tables ready for whole block
}

// ---- fused quant pipeline ----
__global__ __launch_bounds__(256, 2) void k_fused(const float* __restrict__ U,
                                                  const float* __restrict__ x,
                                                  unsigned short* __restrict__ xb,
                                                  unsigned short* __restrict__ vsumb,
                                                  const float* __restrict__ tm,
                                                  unsigned* __restrict__ meta,
                                                  unsigned* __restrict__ bar,
                                                  unsigned* __restrict__ fin){
  #pragma clang fp contract(off)
  __shared__ unsigned redA[256], redB[256];
  __shared__ int hist[128];
  __shared__ float qcol[8*256];            // [row][t] own-lane scatter, bank = t%32 (conflict-free)
  __shared__ int cs[128], rk[128], redk[128];
  __shared__ int top_code[5], top_rank[5];
  __shared__ int w0cnt;
  __shared__ int fr_s[128];
  __shared__ unsigned bits_s[128];
  __shared__ float msp_s[896];
  __shared__ unsigned bcA, bcB;

  const int t = threadIdx.x, b = blockIdx.x;
  const int g = b*256 + t;
  const int lane = t & 63;
  int d[NQ];
  #pragma unroll
  for (int q = 0; q < NQ; ++q) d[q] = 4*g + q*4*NTHR;   // column base per quad (coalesced)

  // ---- P0: zero hists, x->bf16, global min/max of U ----
  if (b == 0 && t < 128){ ast(&meta[4+t], 0u); ast(&meta[132+t], 0u); }
  {
    const float4* x4 = (const float4*)x;   // 2,097,152 float4 over 131,072 threads = 16 each
    #pragma unroll
    for (int i = 0; i < 16; ++i){
      int idx = g + i*NTHR;
      float4 v = x4[idx];
      ushort4 o;
      o.x = f2bf(v.x); o.y = f2bf(v.y); o.z = f2bf(v.z); o.w = f2bf(v.w);
      *(ushort4*)(xb + (size_t)idx*4) = o;
    }
  }
  {
    float mx = -INFINITY, mn = INFINITY;
    #pragma unroll
    for (int q = 0; q < NQ; ++q){
      #pragma unroll
      for (int i = 0; i < 8; ++i){
        float4 v = *(const float4*)(U + (size_t)i*DT + d[q]);
        mx = fmaxf(mx, fmaxf(fmaxf(v.x,v.y), fmaxf(v.z,v.w)));
        mn = fminf(mn, fminf(fminf(v.x,v.y), fminf(v.z,v.w)));
      }
    }
    redA[t] = fenc(mx); redB[t] = fenc(mn);
    __syncthreads();
    for (int o = 128; o > 0; o >>= 1){
      if (t < o){ redA[t] = max(redA[t], redA[t+o]); redB[t] = min(redB[t], redB[t+o]); }
      __syncthreads();
    }
    if (t == 0){ atomicMax(&fin[0], redA[0]); atomicMin(&fin[3], redB[0]); }
  }
  gbar(bar, t, 1*GBLK);

  // ---- s1 (single-word broadcast; max/min order-independent -> bit-identical) ----
  if (t == 0){ bcA = ald(&fin[0]); bcB = ald(&fin[3]); }
  __syncthreads();
  float s1 = (fdec(bcA) - fdec(bcB)) / 3.0f;
  float inv_s1 = 1.0f / s1;
  float s2 = s1 / 5.0f;

  // ---- P1: level-2 delta gmax ----
  {
    unsigned dmax = 0u;
    #pragma unroll
    for (int q = 0; q < NQ; ++q){
      float4 u4[8];
      #pragma unroll
      for (int i = 0; i < 8; ++i) u4[i] = *(const float4*)(U + (size_t)i*DT + d[q]);
      #pragma unroll
      for (int c = 0; c < 4; ++c){
        float res[8];
        #pragma unroll
        for (int i = 0; i < 8; ++i){
          float uv = ((const float*)&u4[i])[c];
          res[i] = uv - base1(uv, s1, inv_s1);
        }
        sort8v(res);
        float m = 0.0f;
        #pragma unroll
        for (int i = 0; i < 7; ++i) m = fmaxf(m, res[i+1] - res[i]);
        dmax = max(dmax, __float_as_uint(m));   // deltas >= 0: bits order-preserving
      }
    }
    unsigned r = blk_umax(dmax, redA, t);
    if (t == 0) atomicMax(&fin[1], r);
  }
  gbar(bar, t, 2*GBLK);
  if (t == 0) bcA = ald(&fin[1]);
  __syncthreads();
  float gmax2 = __uint_as_float(bcA);

  // ---- P2: level-2 codes + histogram (7-ballot match-any) ----
  unsigned cdq[NQ];
  {
    if (t < 128) hist[t] = 0;
    __syncthreads();
    float inv_g = 1.0f / gmax2;
    #pragma unroll
    for (int q = 0; q < NQ; ++q){
      float4 u4[8];
      #pragma unroll
      for (int i = 0; i < 8; ++i) u4[i] = *(const float4*)(U + (size_t)i*DT + d[q]);
      float thr = sigmoid_ref(tm[d[q] >> 11]);
      unsigned cpack = 0u;
      #pragma unroll
      for (int c = 0; c < 4; ++c){
        float res[8];
        #pragma unroll
        for (int i = 0; i < 8; ++i){
          float uv = ((const float*)&u4[i])[c];
          res[i] = uv - base1(uv, s1, inv_s1);
        }
        sort8v(res);
        int cd = 0;
        #pragma unroll
        for (int i = 0; i < 7; ++i){
          float dn = (res[i+1] - res[i]) * inv_g;
          cd = (cd << 1) | ((dn > thr) ? 1 : 0);
        }
        cpack |= (unsigned)cd << (8*c);
        // match-any: fixed-cost 7 ballots, one LDS atomic per distinct code per wave
        unsigned long long mset = ~0ull;
        #pragma unroll
        for (int bi = 0; bi < 7; ++bi){
          bool bit = ((cd >> bi) & 1) != 0;
          unsigned long long bb = __ballot(bit);
          mset &= bit ? bb : ~bb;
        }
        int leader = (int)__ffsll(mset) - 1;
        if (lane == leader) atomicAdd(&hist[cd], (int)__popcll(mset));
      }
      cdq[q] = cpack;
    }
    __syncthreads();
    if (t < 128){ int h = hist[t]; if (h) atomicAdd((int*)&meta[4 + t], h); }
  }
  gbar(bar, t, 3*GBLK);

  // ---- small2: replicated per block -> fr_s/bits_s/msp_s in LDS ----
  small_phase<2>(t, gmax2, 4, s1, inv_s1, s2, U, tm, meta,
                 cs, rk, redk, top_code, top_rank, &w0cnt, fr_s, bits_s, msp_s);

  // ---- P4: level-2 apply -> m nibbles in regs + fused level-3 gmax ----
  unsigned mpk[NQ][4];
  {
    float s = s2, inv_s = 1.0f / s;
    unsigned dmax = 0u;
    #pragma unroll
    for (int q = 0; q < NQ; ++q){
      float4 u4[8];
      #pragma unroll
      for (int i = 0; i < 8; ++i) u4[i] = *(const float4*)(U + (size_t)i*DT + d[q]);
      #pragma unroll
      for (int c = 0; c < 4; ++c){
        float v[8]; int ix[8];
        #pragma unroll
        for (int i = 0; i < 8; ++i){
          float uv = ((const float*)&u4[i])[c];
          v[i] = uv - base1(uv, s1, inv_s1);
          ix[i] = i;
        }
        sort8kv(v, ix);                    // stable: reproduces jnp.argsort
        int cr = fr_s[(cdq[q] >> (8*c)) & 0x7f];
        unsigned sb = bits_s[cr];
        float vv[8]; bool bl[8];
        float buf = 0.0f, cnt = 0.0f, gq = 1.0f; bool reset = false;
        #pragma unroll
        for (int i = 0; i < 8; ++i){       // reference scan; mean via rcp (<=1.5ulp)
          buf = reset ? v[i] : (buf + v[i]);
          cnt = reset ? 1.0f : (cnt + 1.0f);
          gq  = reset ? 1.0f : gq;
          float m = buf * __builtin_amdgcn_rcpf(cnt);
          if (i == 7){ vv[7] = gq * m; bl[7] = true; }
          else {
            float msp = msp_s[cr*7 + i];
            bool bv = ((sb >> i) & 1u) != 0u;
            vv[i] = bv ? ((gq * msp) * m) : 0.0f;
            bl[i] = bv;
            gq = bv ? gq : (gq * (1.0f - msp));
            reset = bv;
          }
        }
        float out = vv[7];
        float inner[8];
        inner[7] = out;
        for (int i = 6; i >= 0; --i){ if (bl[i]) out = vv[i]; inner[i] = out; }
        unsigned mp = 0u;
        #pragma unroll
        for (int i = 0; i < 8; ++i){       // nibble-scatter to original row (no LDS needed)
          float mf = floorf(inner[i] * inv_s);
          int mi = (int)mf;
          mi = max(-8, min(7, mi));
          mp |= (unsigned)(mi + 8) << (4*ix[i]);
        }
        mpk[q][c] = mp;
        float r3[8];
        #pragma unroll
        for (int r = 0; r < 8; ++r){       // bit-exact next-level residual: u - (b + s*mi)
          int mi = (int)((mp >> (4*r)) & 15u) - 8;
          float uv = ((const float*)&u4[r])[c];
          float qv = s * (float)mi;
          float vn = base1(uv, s1, inv_s1) + qv;
          r3[r] = uv - vn;
        }
        sort8v(r3);
        float m = 0.0f;
        #pragma unroll
        for (int i = 0; i < 7; ++i) m = fmaxf(m, r3[i+1] - r3[i]);
        dmax = max(dmax, __float_as_uint(m));
      }
    }
    // publish level-2 m for cols 0..127 (block 0, threads 0..31 own them at q=0)
    if (b == 0 && t < 32){
      #pragma unroll
      for (int c = 0; c < 4; ++c) ast(&meta[1412 + 4*t + c], mpk[0][c]);
    }
    unsigned r = blk_umax(dmax, redA, t);
    if (t == 0) atomicMax(&fin[2], r);
  }
  gbar(bar, t, 4*GBLK);
  if (t == 0) bcA = ald(&fin[2]);
  __syncthreads();
  float gmax3 = __uint_as_float(bcA);

  // ---- P5: level-3 codes + histogram ----
  {
    __syncthreads();
    if (t < 128) hist[t] = 0;
    __syncthreads();
    float inv_g = 1.0f / gmax3;
    #pragma unroll
    for (int q = 0; q < NQ; ++q){
      float4 u4[8];
      #pragma unroll
      for (int i = 0; i < 8; ++i) u4[i] = *(const float4*)(U + (size_t)i*DT + d[q]);
      float thr = sigmoid_ref(tm[d[q] >> 11]);
      unsigned cpack = 0u;
      #pragma unroll
      for (int c = 0; c < 4; ++c){
        float res[8];
        #pragma unroll
        for (int i = 0; i < 8; ++i){
          int mi = (int)((mpk[q][c] >> (4*i)) & 15u) - 8;
          float uv = ((const float*)&u4[i])[c];
          res[i] = uv - (base1(uv, s1, inv_s1) + s2 * (float)mi);   // == vn2_of path
        }
        sort8v(res);
        int cd = 0;
        #pragma unroll
        for (int i = 0; i < 7; ++i){
          float dn = (res[i+1] - res[i]) * inv_g;
          cd = (cd << 1) | ((dn > thr) ? 1 : 0);
        }
        cpack |= (unsigned)cd << (8*c);
        unsigned long long mset = ~0ull;
        #pragma unroll
        for (int bi = 0; bi < 7; ++bi){
          bool bit = ((cd >> bi) & 1) != 0;
          unsigned long long bb = __ballot(bit);
          mset &= bit ? bb : ~bb;
        }
        int leader = (int)__ffsll(mset) - 1;
        if (lane == leader) atomicAdd(&hist[cd], (int)__popcll(mset));
      }
      cdq[q] = cpack;
    }
    __syncthreads();
    if (t < 128){ int h = hist[t]; if (h) atomicAdd((int*)&meta[132 + t], h); }
  }
  gbar(bar, t, 5*GBLK);

  // ---- small3: replicated per block ----
  small_phase<3>(t, gmax3, 132, s1, inv_s1, s2, U, tm, meta,
                 cs, rk, redk, top_code, top_rank, &w0cnt, fr_s, bits_s, msp_s);

  // ---- P7: level-3 apply -> final vsum bf16 [n][k][l] ----
  {
    float s = s2 / 17.0f, inv_s = 1.0f / s;
    #pragma unroll
    for (int q = 0; q < NQ; ++q){
      float4 u4[8];
      #pragma unroll
      for (int i = 0; i < 8; ++i) u4[i] = *(const float4*)(U + (size_t)i*DT + d[q]);
      ushort4 ov[8];
      #pragma unroll
      for (int c = 0; c < 4; ++c){
        float v[8]; int ix[8];
        #pragma unroll
        for (int i = 0; i < 8; ++i){
          int mi = (int)((mpk[q][c] >> (4*i)) & 15u) - 8;
          float uv = ((const float*)&u4[i])[c];
          v[i] = uv - (base1(uv, s1, inv_s1) + s2 * (float)mi);
          ix[i] = i;
        }
        sort8kv(v, ix);
        int cr = fr_s[(cdq[q] >> (8*c)) & 0x7f];
        unsigned sb = bits_s[cr];
        float vv[8]; bool bl[8];
        float buf = 0.0f, cnt = 0.0f, gq = 1.0f; bool reset = false;
        #pragma unroll
        for (int i = 0; i < 8; ++i){
          buf = reset ? v[i] : (buf + v[i]);
          cnt = reset ? 1.0f : (cnt + 1.0f);
          gq  = reset ? 1.0f : gq;
          float m = buf * __builtin_amdgcn_rcpf(cnt);
          if (i == 7){ vv[7] = gq * m; bl[7] = true; }
          else {
            float msp = msp_s[cr*7 + i];
            bool bv = ((sb >> i) & 1u) != 0u;
            vv[i] = bv ? ((gq * msp) * m) : 0.0f;
            bl[i] = bv;
            gq = bv ? gq : (gq * (1.0f - msp));
            reset = bv;
          }
        }
        float out = vv[7];
        float inner[8];
        inner[7] = out;
        for (int i = 6; i >= 0; --i){ if (bl[i]) out = vv[i]; inner[i] = out; }
        // own-lane LDS scatter (float floor-count, unclamped — matches verified level-3 path)
        #pragma unroll
        for (int i = 0; i < 8; ++i) qcol[ix[i]*256 + t] = floorf(inner[i] * inv_s);
        #pragma unroll
        for (int r = 0; r < 8; ++r){
          int mi = (int)((mpk[q][c] >> (4*r)) & 15u) - 8;
          float uv = ((const float*)&u4[r])[c];
          float bv = base1(uv, s1, inv_s1) + s2 * (float)mi;
          float qv = s * qcol[r*256 + t];
          ((unsigned short*)&ov[r])[c] = f2bf(bv + qv);
        }
      }
      #pragma unroll
      for (int r = 0; r < 8; ++r)
        *(ushort4*)(vsumb + (size_t)r*DT + d[q]) = ov[r];
    }
  }
}

// transpose: wt[n][l][k] = vsumb[n][k][l] (both bf16); 64(k) x 64(l) tiles
__global__ __launch_bounds__(256) void k_wt(const unsigned short* __restrict__ vsumb,
                                            unsigned short* __restrict__ wt){
  __shared__ unsigned short tile[64][68];
  int t = threadIdx.x;
  int c4 = t & 15, r0 = t >> 4;
  int n = blockIdx.z, k0 = blockIdx.y*64, l0 = blockIdx.x*64;
  const unsigned short* src = vsumb + (size_t)n*DT;
  #pragma unroll
  for (int i = 0; i < 4; ++i){
    int r = r0 + i*16;                     // k index in tile
    ushort4 v = *(const ushort4*)(src + (size_t)(k0+r)*DD2 + l0 + c4*4);
    *(ushort4*)&tile[r][c4*4] = v;
  }
  __syncthreads();
  unsigned short* dst = wt + (size_t)n*DT;
  #pragma unroll
  for (int i = 0; i < 4; ++i){
    int rl = r0 + i*16;                    // l index in tile
    ushort4 o;
    o.x = tile[c4*4+0][rl]; o.y = tile[c4*4+1][rl];
    o.z = tile[c4*4+2][rl]; o.w = tile[c4*4+3][rl];
    *(ushort4*)(dst + (size_t)(l0+rl)*DD1 + k0 + c4*4) = o;
  }
}

// MFMA GEMM: out[b,n,l] = sum_k xb[b,n,k] * wt[n,l,k]; 64(M)x128(N) tile, BK=64, 4 waves
__global__ __launch_bounds__(256) void k_gemm(const unsigned short* __restrict__ xb,
                                              const unsigned short* __restrict__ wt,
                                              float* __restrict__ out){
  __shared__ __align__(16) unsigned short As[64*64];
  __shared__ __align__(16) unsigned short Bs[128*64];
  int t = threadIdx.x;
  int lane = t & 63, wv = t >> 6;
  int n  = blockIdx.z;
  int b0 = blockIdx.y * 64;
  int l0 = blockIdx.x * 128;
  int wm = (wv >> 1) * 32, wn = (wv & 1) * 64;
  int col = lane & 15, quad = lane >> 4;
  int arow = lane >> 3, aseg = lane & 7;
  const unsigned short* wtn = wt + (size_t)n*DT;
  f32x4 acc[2][4] = {};
  for (int k0 = 0; k0 < DD1; k0 += 64){
    #pragma unroll
    for (int i = 0; i < 2; ++i){
      int row = wv*16 + i*8 + arow;
      const unsigned short* g = xb + (((size_t)(b0+row)*NROW + n)*DD1 + k0 + aseg*8);
      async16(g, &As[(wv*16 + i*8)*64]);
    }
    #pragma unroll
    for (int i = 0; i < 4; ++i){
      int row = wv*32 + i*8 + arow;
      const unsigned short* g = wtn + ((size_t)(l0+row)*DD1 + k0 + aseg*8);
      async16(g, &Bs[(wv*32 + i*8)*64]);
    }
    __syncthreads();
    #pragma unroll
    for (int ks = 0; ks < 2; ++ks){
      int kq = ks*32 + quad*8;
      short8 af[2], bfr[4];
      #pragma unroll
      for (int mi = 0; mi < 2; ++mi) af[mi]  = *(const short8*)&As[(wm + mi*16 + col)*64 + kq];
      #pragma unroll
      for (int ni = 0; ni < 4; ++ni) bfr[ni] = *(const short8*)&Bs[(wn + ni*16 + col)*64 + kq];
      #pragma unroll
      for (int mi = 0; mi < 2; ++mi)
        #pragma unroll
        for (int ni = 0; ni < 4; ++ni)
          acc[mi][ni] = __builtin_amdgcn_mfma_f32_16x16x32_bf16(af[mi], bfr[ni], acc[mi][ni], 0, 0, 0);
    }
    __syncthreads();
  }
  #pragma unroll
  for (int mi = 0; mi < 2; ++mi)
    #pragma unroll
    for (int ni = 0; ni < 4; ++ni)
      #pragma unroll
      for (int r = 0; r < 4; ++r){
        int bb = b0 + wm + mi*16 + quad*4 + r;
        int l = l0 + wn + ni*16 + col;
        out[((size_t)bb*NROW + n)*DD2 + l] = acc[mi][ni][r];
      }
}

extern "C" void kernel_launch(void* const* d_in, const int* in_sizes, int n_in,
                              void* d_out, int out_size, void* d_ws, size_t ws_size,
                              hipStream_t stream){
  const float* x  = (const float*)d_in[0];
  const float* U  = (const float*)d_in[1];
  const float* tm = (const float*)d_in[2];
  float* out = (float*)d_out;
  unsigned short* vsumb = (unsigned short*)((unsigned char*)d_ws + 16777216);
  unsigned short* xb    = (unsigned short*)((unsigned char*)d_ws + 50331648);
  unsigned short* wt    = (unsigned short*)((unsigned char*)d_ws + 69206016);
  unsigned* meta  = (unsigned*)((unsigned char*)d_ws + 102760448);
  unsigned* bar   = (unsigned*)((unsigned char*)d_ws + 102801408);
  unsigned* fin   = (unsigned*)((unsigned char*)d_ws + 102801412);
  (void)in_sizes; (void)n_in; (void)out_size; (void)ws_size;

  hipMemsetAsync(bar, 0, 16, stream);        // bar=0, fin[0..2]=0 (max-init)
  hipMemsetAsync(fin + 3, 0xFF, 4, stream);  // fin[3]=0xFFFFFFFF (min-init)
  k_fused<<<GBLK, 256, 0, stream>>>(U, x, xb, vsumb, tm, meta, bar, fin);
  k_wt  <<<dim3(DD2/64, DD1/64, NROW), 256, 0, stream>>>(vsumb, wt);
  k_gemm<<<dim3(DD2/128, BATCH/64, NROW), 256, 0, stream>>>(xb, wt, out);
}

// Round 6
// 401.288 us; speedup vs baseline: 2.1232x; 1.6037x over previous
//
#include <hip/hip_runtime.h>
#include <hip/hip_bf16.h>
#include <math.h>

#define NROW 8
#define DT   2097152   // D = D1*D2
#define DD1  2048
#define DD2  1024
#define BATCH 512
#define NBLK 2048      // pass kernels: 2048 blocks x 256 thr x 4 cols == DT

// ws layout (~98.0 MiB):
//  [0)          mcode : NROW*DT uint8  level-2 m (+8 bias)
//  [16777216)   vsumb : NROW*DT bf16   final vsum, [n][k][l]
//  [50331648)   xb    : bf16 x
//  [67108864)   code  : DT bytes
//  [69206016)   wt    : NROW*DT bf16   [n][l][k]
//  [102760448)  meta  : u32[1412] (hist2 @4, hist3 @132, final_rank @260,
//                        msp f32[896] @388, bits @1284)
//  [102801408)  fin   : u32[4]: 0=SMAX fenc(max), 1=G2 bits, 2=G3 bits (memset 0),
//                        3=SMIN fenc(min) (memset 0xFF). All via atomicMax/Min.

typedef __attribute__((ext_vector_type(8))) short short8;
typedef __attribute__((ext_vector_type(4))) float f32x4;

__device__ __forceinline__ unsigned fenc(float f){
  unsigned u = __float_as_uint(f);
  return (u & 0x80000000u) ? ~u : (u | 0x80000000u);
}
__device__ __forceinline__ float fdec(unsigned k){
  return (k & 0x80000000u) ? __uint_as_float(k ^ 0x80000000u) : __uint_as_float(~k);
}
__device__ __forceinline__ float sigmoid_ref(float z){
  #pragma clang fp contract(off)
  return 1.0f / (1.0f + expf(-z));
}
__device__ __forceinline__ unsigned short f2bf(float f){
  __hip_bfloat16 h = __float2bfloat16(f);
  return *reinterpret_cast<unsigned short*>(&h);
}
// consistent level-1 base across ALL kernels
__device__ __forceinline__ float base1(float u, float s1, float inv_s1){
  #pragma clang fp contract(off)
  return s1 * floorf(u * inv_s1);
}
// reconstruct level-2 vsum from u + stored m byte (bit-exact vs producer)
__device__ __forceinline__ float vn2_of(float u, unsigned char mb, float s1, float inv_s1, float s2){
  #pragma clang fp contract(off)
  return base1(u, s1, inv_s1) + s2 * (float)((int)mb - 8);
}
__device__ __forceinline__ void async16(const unsigned short* g, unsigned short* l){
  __builtin_amdgcn_global_load_lds((const __attribute__((address_space(1))) unsigned int*)g,
                                   (__attribute__((address_space(3))) unsigned int*)l, 16, 0, 0);
}

// ---- 8-element sorting networks (Batcher odd-even, 19 comparators) ----
#define CSWAPV(a,b) { float _lo=fminf(a,b), _hi=fmaxf(a,b); a=_lo; b=_hi; }
__device__ __forceinline__ void sort8v(float v[8]){
  CSWAPV(v[0],v[1]) CSWAPV(v[2],v[3]) CSWAPV(v[4],v[5]) CSWAPV(v[6],v[7])
  CSWAPV(v[0],v[2]) CSWAPV(v[1],v[3]) CSWAPV(v[4],v[6]) CSWAPV(v[5],v[7])
  CSWAPV(v[1],v[2]) CSWAPV(v[5],v[6])
  CSWAPV(v[0],v[4]) CSWAPV(v[1],v[5]) CSWAPV(v[2],v[6]) CSWAPV(v[3],v[7])
  CSWAPV(v[2],v[4]) CSWAPV(v[3],v[5])
  CSWAPV(v[1],v[2]) CSWAPV(v[3],v[4]) CSWAPV(v[5],v[6])
}
__device__ __forceinline__ void cswapkv(float&av,int&ai,float&bv,int&bi){
  bool sw = (av > bv) || ((av == bv) && (ai > bi));   // lexicographic -> stable
  float nav = sw ? bv : av; float nbv = sw ? av : bv;
  int   nai = sw ? bi : ai; int   nbi = sw ? ai : bi;
  av = nav; bv = nbv; ai = nai; bi = nbi;
}
#define CSWAPK(i,j) cswapkv(v[i],ix[i],v[j],ix[j]);
__device__ __forceinline__ void sort8kv(float v[8], int ix[8]){
  CSWAPK(0,1) CSWAPK(2,3) CSWAPK(4,5) CSWAPK(6,7)
  CSWAPK(0,2) CSWAPK(1,3) CSWAPK(4,6) CSWAPK(5,7)
  CSWAPK(1,2) CSWAPK(5,6)
  CSWAPK(0,4) CSWAPK(1,5) CSWAPK(2,6) CSWAPK(3,7)
  CSWAPK(2,4) CSWAPK(3,5)
  CSWAPK(1,2) CSWAPK(3,4) CSWAPK(5,6)
}

// ---- P1: global min/max of U (-> fin[0]/fin[3]) + x->bf16 + zero hists ----
__global__ __launch_bounds__(256) void k_mmxb(const float* __restrict__ U, const float* __restrict__ x,
                                              unsigned short* __restrict__ xb,
                                              unsigned* __restrict__ meta, unsigned* __restrict__ fin){
  __shared__ unsigned redA[256], redB[256];
  int t = threadIdx.x, b = blockIdx.x;
  int gid = b*256 + t;
  if (b == 0 && t < 128){ meta[4+t] = 0u; meta[132+t] = 0u; }
  // x convert: 2,097,152 float4 over 524,288 threads = 4 each
  const float4* x4 = (const float4*)x;
  #pragma unroll
  for (int i = 0; i < 4; ++i){
    int idx = gid + i*524288;
    float4 v = x4[idx];
    ushort4 o;
    o.x = f2bf(v.x); o.y = f2bf(v.y); o.z = f2bf(v.z); o.w = f2bf(v.w);
    *(ushort4*)(xb + (size_t)idx*4) = o;
  }
  // U min/max: 4,194,304 float4 = 8 each
  const float4* U4 = (const float4*)U;
  float mx = -INFINITY, mn = INFINITY;
  #pragma unroll
  for (int i = 0; i < 8; ++i){
    float4 v = U4[gid + i*524288];
    mx = fmaxf(mx, fmaxf(fmaxf(v.x,v.y), fmaxf(v.z,v.w)));
    mn = fminf(mn, fminf(fminf(v.x,v.y), fminf(v.z,v.w)));
  }
  redA[t] = fenc(mx); redB[t] = fenc(mn);
  __syncthreads();
  for (int o = 128; o > 0; o >>= 1){
    if (t < o){ redA[t] = max(redA[t], redA[t+o]); redB[t] = min(redB[t], redB[t+o]); }
    __syncthreads();
  }
  if (t == 0){ atomicMax(&fin[0], redA[0]); atomicMin(&fin[3], redB[0]); }
}

// ---- P2: level-2 gmax (-> fin[1]) ----
__global__ __launch_bounds__(256) void k_passA2(const float* __restrict__ U,
                                                unsigned* __restrict__ fin){
  #pragma clang fp contract(off)
  __shared__ unsigned red[256];
  int t = threadIdx.x, b = blockIdx.x;
  float s1 = (fdec(fin[0]) - fdec(fin[3])) / 3.0f;   // identical expr to old k_fin<0>
  float inv_s1 = 1.0f / s1;
  int d0 = (b*256 + t)*4;
  float4 u[8];
  #pragma unroll
  for (int i = 0; i < 8; ++i) u[i] = *(const float4*)(U + (size_t)i*DT + d0);
  unsigned dmax = 0u;
  #pragma unroll
  for (int c = 0; c < 4; ++c){
    float res[8];
    #pragma unroll
    for (int i = 0; i < 8; ++i){
      float uv = ((const float*)&u[i])[c];
      res[i] = uv - base1(uv, s1, inv_s1);
    }
    sort8v(res);
    float m = 0.0f;
    #pragma unroll
    for (int i = 0; i < 7; ++i) m = fmaxf(m, res[i+1] - res[i]);
    dmax = max(dmax, __float_as_uint(m));   // deltas >= 0: bits order-preserving
  }
  red[t] = dmax;
  __syncthreads();
  for (int o = 128; o > 0; o >>= 1){
    if (t < o) red[t] = max(red[t], red[t+o]);
    __syncthreads();
  }
  if (t == 0) atomicMax(&fin[1], red[0]);
}

// ---- P3/P6: codes + histogram (7-ballot match-any: fixed cost, no serial chain) ----
template<int LEVEL>
__global__ __launch_bounds__(256) void k_passB(const float* __restrict__ U,
                                               const unsigned char* __restrict__ mcode,
                                               const float* __restrict__ tm,
                                               unsigned char* __restrict__ code,
                                               unsigned* __restrict__ meta,
                                               const unsigned* __restrict__ fin){
  #pragma clang fp contract(off)
  __shared__ int hist[128];
  int t = threadIdx.x, b = blockIdx.x;
  int lane = t & 63;
  if (t < 128) hist[t] = 0;
  float s1 = (fdec(fin[0]) - fdec(fin[3])) / 3.0f;
  float inv_s1 = 1.0f / s1;
  float s2 = s1 / 5.0f;
  float gmax = __uint_as_float(fin[(LEVEL==2)?1:2]);
  float inv_gmax = 1.0f / gmax;
  int d0 = (b*256 + t)*4;
  float4 u[8], bb[8];
  #pragma unroll
  for (int i = 0; i < 8; ++i){
    u[i] = *(const float4*)(U + (size_t)i*DT + d0);
    if (LEVEL == 2){
      bb[i].x = base1(u[i].x, s1, inv_s1); bb[i].y = base1(u[i].y, s1, inv_s1);
      bb[i].z = base1(u[i].z, s1, inv_s1); bb[i].w = base1(u[i].w, s1, inv_s1);
    } else {
      uchar4 m4 = *(const uchar4*)(mcode + (size_t)i*DT + d0);
      bb[i].x = vn2_of(u[i].x, m4.x, s1, inv_s1, s2);
      bb[i].y = vn2_of(u[i].y, m4.y, s1, inv_s1, s2);
      bb[i].z = vn2_of(u[i].z, m4.z, s1, inv_s1, s2);
      bb[i].w = vn2_of(u[i].w, m4.w, s1, inv_s1, s2);
    }
  }
  __syncthreads();   // hist zeroed before any atomics
  float thr = sigmoid_ref(tm[d0 >> 11]);
  uchar4 cods;
  unsigned char* cp = (unsigned char*)&cods;
  #pragma unroll
  for (int c = 0; c < 4; ++c){
    float res[8];
    #pragma unroll
    for (int i = 0; i < 8; ++i) res[i] = ((const float*)&u[i])[c] - ((const float*)&bb[i])[c];
    sort8v(res);
    int cd = 0;
    #pragma unroll
    for (int i = 0; i < 7; ++i){
      // bit = rint(sigmoid((dn-thr)/0.01)) == (dn > thr)
      float dn = (res[i+1] - res[i]) * inv_gmax;
      cd = (cd << 1) | ((dn > thr) ? 1 : 0);
    }
    cp[c] = (unsigned char)cd;
    // match-any: 7 ballots -> lanes-with-same-code mask; one LDS atomic per distinct code
    unsigned long long mset = ~0ull;
    #pragma unroll
    for (int bi = 0; bi < 7; ++bi){
      bool bit = ((cd >> bi) & 1) != 0;
      unsigned long long bbm = __ballot(bit);
      mset &= bit ? bbm : ~bbm;
    }
    int leader = (int)__ffsll(mset) - 1;
    if (lane == leader) atomicAdd(&hist[cd], (int)__popcll(mset));
  }
  *(uchar4*)(code + d0) = cods;
  __syncthreads();
  if (t < 128){ int h = hist[t]; if (h) atomicAdd((int*)&meta[((LEVEL==2)?4:132) + t], h); }
}

// ---- P4/P7: rank/top-5/msp tables (1 block, 128 threads) ----
template<int LEVEL>
__global__ void k_small(const float* __restrict__ U, const unsigned char* __restrict__ mcode,
                        const float* __restrict__ tm, unsigned* __restrict__ meta,
                        const unsigned* __restrict__ fin){
  #pragma clang fp contract(off)
  __shared__ int cs[128], rk[128], redk[128];
  __shared__ int top_code[5], top_rank[5];
  __shared__ int w0cnt;
  int c = threadIdx.x;                    // 128 threads
  float s1 = (fdec(fin[0]) - fdec(fin[3])) / 3.0f;
  float inv_s1 = 1.0f / s1;
  float s2 = s1 / 5.0f;
  float gmax = __uint_as_float(fin[(LEVEL==2)?1:2]);
  cs[c] = (int)meta[((LEVEL==2)?4:132) + c];
  bool present = cs[c] > 0;
  unsigned long long bm = __ballot(present);
  int lane = c & 63;
  int r = (int)__popcll(bm & ((1ull << lane) - 1ull));
  if (c == 63) w0cnt = (int)__popcll(bm);
  __syncthreads();
  if (c >= 64) r += w0cnt;
  rk[c] = r;
  __syncthreads();
  for (int k = 0; k < 5; ++k){            // top-5 argsort(-counts), ties -> lowest index
    redk[c] = (cs[c] << 7) | (127 - c);
    __syncthreads();
    for (int o = 64; o > 0; o >>= 1){
      if (c < o) redk[c] = max(redk[c], redk[c+o]);
      __syncthreads();
    }
    if (c == 0){
      int best = 127 - (redk[0] & 127);
      top_code[k] = best; top_rank[k] = rk[best];
      cs[best] = -1;
    }
    __syncthreads();
  }
  int besti = -1, sel = 0;
  #pragma unroll
  for (int j = 0; j < 5; ++j){            // argmax first-wins over shared-bit counts
    int inter = __popc(c & top_code[j]);
    if (inter > besti){ besti = inter; sel = j; }
  }
  bool is_top = false;
  #pragma unroll
  for (int j = 0; j < 5; ++j) is_top = is_top || (rk[c] == top_rank[j]);
  ((int*)meta)[260 + c] = is_top ? rk[c] : top_rank[sel];
  // full-fidelity msp/scheme for columns 0..127 (values multiply into w)
  float res[8];
  #pragma unroll
  for (int i = 0; i < 8; ++i){
    size_t off = (size_t)i*DT + c;
    float u = U[off];
    float bval = (LEVEL==2) ? base1(u, s1, inv_s1) : vn2_of(u, mcode[off], s1, inv_s1, s2);
    res[i] = u - bval;
  }
  sort8v(res);
  float thr = sigmoid_ref(tm[c >> 11]);
  unsigned bits = 0;
  float* msp_tab = (float*)(meta + 388);
  #pragma unroll
  for (int i = 0; i < 7; ++i){
    float dn  = (res[i+1] - res[i]) / gmax;
    float z   = (dn - thr) / 0.01f;
    float msp = sigmoid_ref(z);
    msp_tab[c*7 + i] = msp;
    bits |= ((unsigned)(int)rintf(msp)) << i;
  }
  meta[1284 + c] = bits;
}

// ---- P5/P8: quant apply.
//   LEVEL==2: nibble-pack scatter in registers (no 32KB LDS), write mcode + fused gmax3.
//   LEVEL==3: per-column 8KB own-lane LDS scatter, write final vsum bf16 [n][k][l]. ----
template<int LEVEL>
__global__ __launch_bounds__(256) void k_passD(const float* __restrict__ U,
                                               unsigned char* __restrict__ mcode,
                                               unsigned short* __restrict__ vsumb,
                                               const unsigned char* __restrict__ code,
                                               unsigned* __restrict__ meta,
                                               unsigned* __restrict__ fin){
  #pragma clang fp contract(off)
  __shared__ float qcol[8*256];            // LEVEL==3: [row][t] own-lane slots, bank=t%32
  __shared__ unsigned red[256];
  __shared__ int fr_s[128];
  __shared__ unsigned bits_s[128];
  __shared__ float msp_s[896];
  int t = threadIdx.x, b = blockIdx.x;
  float s1 = (fdec(fin[0]) - fdec(fin[3])) / 3.0f;
  float inv_s1 = 1.0f / s1;
  float s2 = s1 / 5.0f;
  float s  = (LEVEL == 2) ? s2 : (s2 / 17.0f);
  float inv_s = 1.0f / s;
  if (t < 128){ fr_s[t] = ((const int*)meta)[260+t]; bits_s[t] = meta[1284+t]; }
  for (int i = t; i < 896; i += 256) msp_s[i] = ((const float*)(meta+388))[i];
  __syncthreads();
  int d0 = (b*256 + t)*4;
  float4 u4[8];
  uchar4 m4[8];
  #pragma unroll
  for (int i = 0; i < 8; ++i){
    u4[i] = *(const float4*)(U + (size_t)i*DT + d0);
    if (LEVEL == 3) m4[i] = *(const uchar4*)(mcode + (size_t)i*DT + d0);
  }
  uchar4 cods = *(const uchar4*)(code + d0);
  const unsigned char* cp = (const unsigned char*)&cods;
  uchar4 mout[8];
  ushort4 ov[8];
  unsigned dmax = 0u;
  #pragma unroll
  for (int c = 0; c < 4; ++c){
    float v[8]; int ix[8];
    #pragma unroll
    for (int i = 0; i < 8; ++i){
      float uv = ((const float*)&u4[i])[c];
      float bval;
      if (LEVEL == 2) bval = base1(uv, s1, inv_s1);
      else {
        int mi = (int)((const unsigned char*)&m4[i])[c] - 8;
        bval = base1(uv, s1, inv_s1) + s2 * (float)mi;
      }
      v[i] = uv - bval;
      ix[i] = i;
    }
    sort8kv(v, ix);                        // stable: reproduces jnp.argsort
    int cr = fr_s[cp[c]];
    unsigned sb = bits_s[cr];
    float vv[8]; bool bl[8];
    float buf = 0.0f, cnt = 0.0f, g = 1.0f; bool reset = false;
    #pragma unroll
    for (int i = 0; i < 8; ++i){           // reference scan; mean via rcp (<=1.5ulp)
      buf = reset ? v[i] : (buf + v[i]);
      cnt = reset ? 1.0f : (cnt + 1.0f);
      g   = reset ? 1.0f : g;
      float m = buf * __builtin_amdgcn_rcpf(cnt);
      if (i == 7){ vv[7] = g * m; bl[7] = true; }
      else {
        float msp = msp_s[cr*7 + i];
        bool bv = ((sb >> i) & 1u) != 0u;
        vv[i] = bv ? ((g * msp) * m) : 0.0f;
        bl[i] = bv;
        g = bv ? g : (g * (1.0f - msp));
        reset = bv;
      }
    }
    float out = vv[7];
    float inner[8];
    inner[7] = out;
    for (int i = 6; i >= 0; --i){ if (bl[i]) out = vv[i]; inner[i] = out; }
    if (LEVEL == 2){
      // nibble-scatter to original row in registers (verified in fused R2-R5)
      unsigned mp = 0u;
      #pragma unroll
      for (int i = 0; i < 8; ++i){
        float mf = floorf(inner[i] * inv_s);
        int mi = (int)mf;
        mi = max(-8, min(7, mi));
        mp |= (unsigned)(mi + 8) << (4*ix[i]);
      }
      float res3[8];
      #pragma unroll
      for (int r = 0; r < 8; ++r){         // bit-exact next-level residual: u - (b + s*mi)
        int mi = (int)((mp >> (4*r)) & 15u) - 8;
        ((unsigned char*)&mout[r])[c] = (unsigned char)(mi + 8);
        float uv = ((const float*)&u4[r])[c];
        float qv = s * (float)mi;
        float vn = base1(uv, s1, inv_s1) + qv;
        res3[r] = uv - vn;
      }
      sort8v(res3);
      float m = 0.0f;
      #pragma unroll
      for (int i = 0; i < 7; ++i) m = fmaxf(m, res3[i+1] - res3[i]);
      dmax = max(dmax, __float_as_uint(m));
    } else {
      // own-lane LDS scatter (float floor-count, unclamped — verified level-3 path)
      #pragma unroll
      for (int i = 0; i < 8; ++i) qcol[ix[i]*256 + t] = floorf(inner[i] * inv_s);
      #pragma unroll
      for (int r = 0; r < 8; ++r){
        int mi = (int)((const unsigned char*)&m4[r])[c] - 8;
        float uv = ((const float*)&u4[r])[c];
        float bv = base1(uv, s1, inv_s1) + s2 * (float)mi;
        float qv = s * qcol[r*256 + t];
        ((unsigned short*)&ov[r])[c] = f2bf(bv + qv);
      }
    }
  }
  if (LEVEL == 2){
    #pragma unroll
    for (int r = 0; r < 8; ++r)
      *(uchar4*)(mcode + (size_t)r*DT + d0) = mout[r];
    red[t] = dmax;
    __syncthreads();
    for (int o = 128; o > 0; o >>= 1){
      if (t < o) red[t] = max(red[t], red[t+o]);
      __syncthreads();
    }
    if (t == 0) atomicMax(&fin[2], red[0]);
  } else {
    #pragma unroll
    for (int r = 0; r < 8; ++r)
      *(ushort4*)(vsumb + (size_t)r*DT + d0) = ov[r];
  }
}

// transpose: wt[n][l][k] = vsumb[n][k][l] (both bf16); 64(k) x 64(l) tiles
__global__ __launch_bounds__(256) void k_wt(const unsigned short* __restrict__ vsumb,
                                            unsigned short* __restrict__ wt){
  __shared__ unsigned short tile[64][68];
  int t = threadIdx.x;
  int c4 = t & 15, r0 = t >> 4;
  int n = blockIdx.z, k0 = blockIdx.y*64, l0 = blockIdx.x*64;
  const unsigned short* src = vsumb + (size_t)n*DT;
  #pragma unroll
  for (int i = 0; i < 4; ++i){
    int r = r0 + i*16;                     // k index in tile
    ushort4 v = *(const ushort4*)(src + (size_t)(k0+r)*DD2 + l0 + c4*4);
    *(ushort4*)&tile[r][c4*4] = v;
  }
  __syncthreads();
  unsigned short* dst = wt + (size_t)n*DT;
  #pragma unroll
  for (int i = 0; i < 4; ++i){
    int rl = r0 + i*16;                    // l index in tile
    ushort4 o;
    o.x = tile[c4*4+0][rl]; o.y = tile[c4*4+1][rl];
    o.z = tile[c4*4+2][rl]; o.w = tile[c4*4+3][rl];
    *(ushort4*)(dst + (size_t)(l0+rl)*DD1 + k0 + c4*4) = o;
  }
}

// MFMA GEMM: out[b,n,l] = sum_k xb[b,n,k] * wt[n,l,k]; 64(M)x128(N) tile, BK=64, 4 waves
__global__ __launch_bounds__(256) void k_gemm(const unsigned short* __restrict__ xb,
                                              const unsigned short* __restrict__ wt,
                                              float* __restrict__ out){
  __shared__ __align__(16) unsigned short As[64*64];
  __shared__ __align__(16) unsigned short Bs[128*64];
  int t = threadIdx.x;
  int lane = t & 63, wv = t >> 6;
  int n  = blockIdx.z;
  int b0 = blockIdx.y * 64;
  int l0 = blockIdx.x * 128;
  int wm = (wv >> 1) * 32, wn = (wv & 1) * 64;
  int col = lane & 15, quad = lane >> 4;
  int arow = lane >> 3, aseg = lane & 7;
  const unsigned short* wtn = wt + (size_t)n*DT;
  f32x4 acc[2][4] = {};
  for (int k0 = 0; k0 < DD1; k0 += 64){
    #pragma unroll
    for (int i = 0; i < 2; ++i){
      int row = wv*16 + i*8 + arow;
      const unsigned short* g = xb + (((size_t)(b0+row)*NROW + n)*DD1 + k0 + aseg*8);
      async16(g, &As[(wv*16 + i*8)*64]);
    }
    #pragma unroll
    for (int i = 0; i < 4; ++i){
      int row = wv*32 + i*8 + arow;
      const unsigned short* g = wtn + ((size_t)(l0+row)*DD1 + k0 + aseg*8);
      async16(g, &Bs[(wv*32 + i*8)*64]);
    }
    __syncthreads();
    #pragma unroll
    for (int ks = 0; ks < 2; ++ks){
      int kq = ks*32 + quad*8;
      short8 af[2], bfr[4];
      #pragma unroll
      for (int mi = 0; mi < 2; ++mi) af[mi]  = *(const short8*)&As[(wm + mi*16 + col)*64 + kq];
      #pragma unroll
      for (int ni = 0; ni < 4; ++ni) bfr[ni] = *(const short8*)&Bs[(wn + ni*16 + col)*64 + kq];
      #pragma unroll
      for (int mi = 0; mi < 2; ++mi)
        #pragma unroll
        for (int ni = 0; ni < 4; ++ni)
          acc[mi][ni] = __builtin_amdgcn_mfma_f32_16x16x32_bf16(af[mi], bfr[ni], acc[mi][ni], 0, 0, 0);
    }
    __syncthreads();
  }
  #pragma unroll
  for (int mi = 0; mi < 2; ++mi)
    #pragma unroll
    for (int ni = 0; ni < 4; ++ni)
      #pragma unroll
      for (int r = 0; r < 4; ++r){
        int bb = b0 + wm + mi*16 + quad*4 + r;
        int l = l0 + wn + ni*16 + col;
        out[((size_t)bb*NROW + n)*DD2 + l] = acc[mi][ni][r];
      }
}

extern "C" void kernel_launch(void* const* d_in, const int* in_sizes, int n_in,
                              void* d_out, int out_size, void* d_ws, size_t ws_size,
                              hipStream_t stream){
  const float* x  = (const float*)d_in[0];
  const float* U  = (const float*)d_in[1];
  const float* tm = (const float*)d_in[2];
  float* out = (float*)d_out;
  unsigned char*  mcode = (unsigned char*)d_ws;
  unsigned short* vsumb = (unsigned short*)((unsigned char*)d_ws + 16777216);
  unsigned short* xb    = (unsigned short*)((unsigned char*)d_ws + 50331648);
  unsigned char*  code  = (unsigned char*)d_ws + 67108864;
  unsigned short* wt    = (unsigned short*)((unsigned char*)d_ws + 69206016);
  unsigned* meta  = (unsigned*)((unsigned char*)d_ws + 102760448);
  unsigned* fin   = (unsigned*)((unsigned char*)d_ws + 102801408);
  (void)in_sizes; (void)n_in; (void)out_size; (void)ws_size;

  hipMemsetAsync(fin, 0, 12, stream);        // fin[0..2]=0 (max-init)
  hipMemsetAsync(fin + 3, 0xFF, 4, stream);  // fin[3]=0xFFFFFFFF (min-init)
  k_mmxb    <<<NBLK, 256, 0, stream>>>(U, x, xb, meta, fin);
  // level 2 (deno = 5)
  k_passA2  <<<NBLK, 256, 0, stream>>>(U, fin);
  k_passB<2><<<NBLK, 256, 0, stream>>>(U, mcode, tm, code, meta, fin);
  k_small<2><<<1,   128, 0, stream>>>(U, mcode, tm, meta, fin);
  k_passD<2><<<NBLK, 256, 0, stream>>>(U, mcode, vsumb, code, meta, fin);  // + fused gmax3
  // level 3 (deno = 17)
  k_passB<3><<<NBLK, 256, 0, stream>>>(U, mcode, tm, code, meta, fin);
  k_small<3><<<1,   128, 0, stream>>>(U, mcode, tm, meta, fin);
  k_passD<3><<<NBLK, 256, 0, stream>>>(U, mcode, vsumb, code, meta, fin);
  // epilogue
  k_wt  <<<dim3(DD2/64, DD1/64, NROW), 256, 0, stream>>>(vsumb, wt);
  k_gemm<<<dim3(DD2/128, BATCH/64, NROW), 256, 0, stream>>>(xb, wt, out);
}